// Round 1
// baseline (765.305 us; speedup 1.0000x reference)
//
#include <hip/hip_runtime.h>

// RiRoIAlign on gfx950.
// features: (2, 256, 256, 256) f32, layout ch = c*8 + o (C=32 outer, O=8 inner)
// rois: (512, 6) f32: [batch, cx, cy, w, h, theta]
// out: (512, 256, 7, 7) f32, out[r, c*8+o, py, px]
//
// One block handles (roi, half of the 32 channels). All 8 orientation planes
// are gathered once per (c,bin) and combined:
//   out[o=(ind+j)&7] = 0.25 * (rvar*v[j] + lvar*v[(j+1)&7])
// which halves gathers vs. the reference's per-o double gather.

#define NS 196          // 14*14 sample points per roi
#define HW 65536        // 256*256
#define TWO_PI_F 6.283185307179586f

__global__ __launch_bounds__(256) void riroi_kernel(
    const float* __restrict__ feat, const float* __restrict__ rois,
    float* __restrict__ out)
{
    const int r = blockIdx.x >> 1;
    const int chunk = blockIdx.x & 1;   // chunk 0: c 0..15, chunk 1: c 16..31
    const int tid = threadIdx.x;

    const float* roi = rois + r * 6;
    const int   b  = (int)roi[0];
    const float cw = roi[1] * 0.125f;
    const float ch = roi[2] * 0.125f;
    const float rw = fmaxf(roi[3] * 0.125f, 1.0f);
    const float rh = fmaxf(roi[4] * 0.125f, 1.0f);
    const float theta = roi[5];

    // orientation interpolation — match reference fp32 arithmetic exactly
    const float ind_f = theta * 8.0f / TWO_PI_F;   // true division (IEEE), like jnp
    const float fl    = floorf(ind_f);
    const float lvar  = ind_f - fl;
    const float rvar  = 1.0f - lvar;
    int ii = (int)fl;
    const int ind = ((ii % 8) + 8) & 7;            // python-mod semantics

    const float cost = cosf(theta), sint = sinf(theta);
    const float bin_h = rh / 7.0f, bin_w = rw / 7.0f;

    __shared__ int   s_off[4][NS];   // y*W + x for corners 00,01,10,11
    __shared__ float s_w[4][NS];     // bilinear weights (incl. validity mask)

    if (tid < NS) {
        int iy = tid / 14, ix = tid - iy * 14;      // iy = py*2+gy, ix = px*2+gx
        int py = iy >> 1, gy = iy & 1;
        int px = ix >> 1, gx = ix & 1;
        // match reference: yy = -rh/2 + (pidx + (g+0.5)/G) * bin_h
        float yy = ((float)py + ((float)gy + 0.5f) * 0.5f) * bin_h - rh * 0.5f;
        float xx = ((float)px + ((float)gx + 0.5f) * 0.5f) * bin_w - rw * 0.5f;
        float x = xx * cost - yy * sint + cw;
        float y = xx * sint + yy * cost + ch;
        float vm = (y > -1.0f && y < 256.0f && x > -1.0f && x < 256.0f) ? 1.0f : 0.0f;
        float yc = fmaxf(y, 0.0f), xc = fmaxf(x, 0.0f);
        int y0 = (int)yc, x0 = (int)xc;
        int y1, x1; float yv, xv;
        if (y0 >= 255) { y0 = 255; y1 = 255; yv = 255.0f; }
        else           { y1 = y0 + 1; yv = yc; }
        if (x0 >= 255) { x0 = 255; x1 = 255; xv = 255.0f; }
        else           { x1 = x0 + 1; xv = xc; }
        float ly = yv - (float)y0, lx = xv - (float)x0;
        float hy = 1.0f - ly, hx = 1.0f - lx;
        s_w[0][tid] = hy * hx * vm;
        s_w[1][tid] = hy * lx * vm;
        s_w[2][tid] = ly * hx * vm;
        s_w[3][tid] = ly * lx * vm;
        int y0w = y0 << 8, y1w = y1 << 8;
        s_off[0][tid] = y0w + x0;
        s_off[1][tid] = y0w + x1;
        s_off[2][tid] = y1w + x0;
        s_off[3][tid] = y1w + x1;
    }
    __syncthreads();

    const float* fb = feat + (size_t)b * (256 * HW);

    const int ibeg = chunk * 784, iend = ibeg + 784;   // 784 = 16 channels * 49 bins
    for (int i = ibeg + tid; i < iend; i += 256) {
        int c   = i / 49;
        int bin = i - c * 49;
        int py  = bin / 7;
        int px  = bin - py * 7;
        int sbase = py * 28 + px * 2;
        const int ss[4] = { sbase, sbase + 1, sbase + 14, sbase + 15 };

        int   off[4][4];
        float w[4][4];
        #pragma unroll
        for (int k = 0; k < 4; ++k) {
            #pragma unroll
            for (int cn = 0; cn < 4; ++cn) {
                off[k][cn] = s_off[cn][ss[k]];
                w[k][cn]   = s_w[cn][ss[k]];
            }
        }

        const float* fc = fb + (size_t)c * (8 * HW);
        float v[8];
        #pragma unroll
        for (int p = 0; p < 8; ++p) {
            const float* fp = fc + p * HW;
            float acc = 0.0f;
            #pragma unroll
            for (int k = 0; k < 4; ++k) {
                acc += w[k][0] * fp[off[k][0]]
                     + w[k][1] * fp[off[k][1]]
                     + w[k][2] * fp[off[k][2]]
                     + w[k][3] * fp[off[k][3]];
            }
            v[p] = acc;
        }

        float* ob = out + ((size_t)r * 256 + (size_t)c * 8) * 49 + bin;
        #pragma unroll
        for (int j = 0; j < 8; ++j) {
            int o = (ind + j) & 7;                         // orientation for plane j
            float res = 0.25f * (rvar * v[j] + lvar * v[(j + 1) & 7]);
            ob[(size_t)o * 49] = res;
        }
    }
}

extern "C" void kernel_launch(void* const* d_in, const int* in_sizes, int n_in,
                              void* d_out, int out_size, void* d_ws, size_t ws_size,
                              hipStream_t stream) {
    const float* feat = (const float*)d_in[0];   // 2*256*256*256
    const float* rois = (const float*)d_in[1];   // 512*6
    float* out = (float*)d_out;                  // 512*256*7*7
    riroi_kernel<<<dim3(512 * 2), dim3(256), 0, stream>>>(feat, rois, out);
}

// Round 2
// 329.982 us; speedup vs baseline: 2.3192x; 2.3192x over previous
//
#include <hip/hip_runtime.h>

// RiRoIAlign on gfx950 — round 2.
// Path A (needs ws >= 134 MB): transpose features NCHW->NHWC into d_ws, then
// gather with one fully-coalesced 1KB load per (sample corner): wave64 x float4
// covers all 256 channels at one (y,x). Orientation blend done with in-lane
// element shifts + one shfl_xor for the wrap element.
// Path B (fallback): round-1 kernel.

#define NS 196          // 14*14 sample points per roi
#define HW 65536        // 256*256
#define TWO_PI_F 6.283185307179586f

// ---------------- transpose: feat[b][ch][p] -> ft[b][p][ch] ----------------
__global__ __launch_bounds__(256) void transpose_kernel(
    const float* __restrict__ in, float* __restrict__ out)
{
    __shared__ float lds[64][65];
    const int tc = blockIdx.x;   // pixel tile (64 wide)
    const int tr = blockIdx.y;   // channel tile (64)
    const int b  = blockIdx.z;
    const int tid = threadIdx.x;

    const float* ip = in  + (size_t)b * 256 * HW;
    float*       op = out + (size_t)b * HW * 256;

    {
        int rr  = tid >> 4;          // 0..15
        int cc4 = (tid & 15) << 2;   // 0,4,..,60
        #pragma unroll
        for (int k = 0; k < 4; ++k) {
            int r = rr + (k << 4);
            const float4 v = *(const float4*)(ip + (size_t)(tr * 64 + r) * HW + tc * 64 + cc4);
            lds[r][cc4]     = v.x;
            lds[r][cc4 + 1] = v.y;
            lds[r][cc4 + 2] = v.z;
            lds[r][cc4 + 3] = v.w;
        }
    }
    __syncthreads();
    {
        int r4   = (tid & 15) << 2;  // 0,4,..,60 (channel within tile)
        int cseg = tid >> 4;         // 0..15
        #pragma unroll
        for (int k = 0; k < 4; ++k) {
            int c = cseg + (k << 4);
            float4 v;
            v.x = lds[r4][c]; v.y = lds[r4 + 1][c];
            v.z = lds[r4 + 2][c]; v.w = lds[r4 + 3][c];
            *(float4*)(op + (size_t)(tc * 64 + c) * 256 + tr * 64 + r4) = v;
        }
    }
}

// ---------------- gather from NHWC ----------------
__global__ __launch_bounds__(256) void riroi_gather(
    const float* __restrict__ ft, const float* __restrict__ rois,
    float* __restrict__ out)
{
    const int r = blockIdx.x;
    const int tid = threadIdx.x;
    const int lane = tid & 63;
    const int wave = tid >> 6;

    const float* roi = rois + r * 6;
    const int   b  = (int)roi[0];
    const float cw = roi[1] * 0.125f;
    const float ch = roi[2] * 0.125f;
    const float rw = fmaxf(roi[3] * 0.125f, 1.0f);
    const float rh = fmaxf(roi[4] * 0.125f, 1.0f);
    const float theta = roi[5];

    const float ind_f = theta * 8.0f / TWO_PI_F;
    const float fl    = floorf(ind_f);
    const float lvar  = ind_f - fl;
    const float rvar  = 1.0f - lvar;
    int ii = (int)fl;
    const int ind = ((ii % 8) + 8) & 7;

    const float cost = cosf(theta), sint = sinf(theta);
    const float bin_h = rh / 7.0f, bin_w = rw / 7.0f;

    __shared__ int   s_off[4][NS];
    __shared__ float s_w[4][NS];

    if (tid < NS) {
        int iy = tid / 14, ix = tid - iy * 14;
        int py = iy >> 1, gy = iy & 1;
        int px = ix >> 1, gx = ix & 1;
        float yy = ((float)py + ((float)gy + 0.5f) * 0.5f) * bin_h - rh * 0.5f;
        float xx = ((float)px + ((float)gx + 0.5f) * 0.5f) * bin_w - rw * 0.5f;
        float x = xx * cost - yy * sint + cw;
        float y = xx * sint + yy * cost + ch;
        float vm = (y > -1.0f && y < 256.0f && x > -1.0f && x < 256.0f) ? 1.0f : 0.0f;
        float yc = fmaxf(y, 0.0f), xc = fmaxf(x, 0.0f);
        int y0 = (int)yc, x0 = (int)xc;
        int y1, x1; float yv, xv;
        if (y0 >= 255) { y0 = 255; y1 = 255; yv = 255.0f; }
        else           { y1 = y0 + 1; yv = yc; }
        if (x0 >= 255) { x0 = 255; x1 = 255; xv = 255.0f; }
        else           { x1 = x0 + 1; xv = xc; }
        float ly = yv - (float)y0, lx = xv - (float)x0;
        float hy = 1.0f - ly, hx = 1.0f - lx;
        s_w[0][tid] = hy * hx * vm;
        s_w[1][tid] = hy * lx * vm;
        s_w[2][tid] = ly * hx * vm;
        s_w[3][tid] = ly * lx * vm;
        int y0w = y0 << 8, y1w = y1 << 8;
        s_off[0][tid] = y0w + x0;
        s_off[1][tid] = y0w + x1;
        s_off[2][tid] = y1w + x0;
        s_off[3][tid] = y1w + x1;
    }
    __syncthreads();

    const float* fb = ft + (size_t)b * ((size_t)HW * 256);

    for (int bin = wave; bin < 49; bin += 4) {
        int py = bin / 7, px = bin - py * 7;
        int sbase = py * 28 + px * 2;
        float4 acc = make_float4(0.f, 0.f, 0.f, 0.f);
        #pragma unroll
        for (int k = 0; k < 4; ++k) {
            int s = sbase + ((k & 1) ? 1 : 0) + ((k & 2) ? 14 : 0);
            #pragma unroll
            for (int cn = 0; cn < 4; ++cn) {
                int   o = s_off[cn][s];
                float w = s_w[cn][s];
                const float4 f = *(const float4*)(fb + (size_t)o * 256 + (lane << 2));
                acc.x += w * f.x; acc.y += w * f.y;
                acc.z += w * f.z; acc.w += w * f.w;
            }
        }
        // orientation blend: lane holds ch_in = 4*lane + i (i=0..3), j = ch_in & 7.
        // next-plane value for i<3 is the next element; for i=3 it is element 0
        // of lane^1 (handles both the +1 step and the j==7 wrap).
        float nx = __shfl_xor(acc.x, 1);
        float4 res;
        res.x = 0.25f * (rvar * acc.x + lvar * acc.y);
        res.y = 0.25f * (rvar * acc.y + lvar * acc.z);
        res.z = 0.25f * (rvar * acc.z + lvar * acc.w);
        res.w = 0.25f * (rvar * acc.w + lvar * nx);

        const int ch0 = lane << 2;
        float* ob = out + (size_t)r * 12544 + bin;
        float vals[4] = { res.x, res.y, res.z, res.w };
        #pragma unroll
        for (int i = 0; i < 4; ++i) {
            int ch_in  = ch0 + i;
            int o      = (ind + (ch_in & 7)) & 7;
            int ch_out = (ch_in & ~7) | o;
            ob[ch_out * 49] = vals[i];
        }
    }
}

// ---------------- fallback (round-1): direct NCHW gather ----------------
__global__ __launch_bounds__(256) void riroi_kernel(
    const float* __restrict__ feat, const float* __restrict__ rois,
    float* __restrict__ out)
{
    const int r = blockIdx.x >> 1;
    const int chunk = blockIdx.x & 1;
    const int tid = threadIdx.x;

    const float* roi = rois + r * 6;
    const int   b  = (int)roi[0];
    const float cw = roi[1] * 0.125f;
    const float ch = roi[2] * 0.125f;
    const float rw = fmaxf(roi[3] * 0.125f, 1.0f);
    const float rh = fmaxf(roi[4] * 0.125f, 1.0f);
    const float theta = roi[5];

    const float ind_f = theta * 8.0f / TWO_PI_F;
    const float fl    = floorf(ind_f);
    const float lvar  = ind_f - fl;
    const float rvar  = 1.0f - lvar;
    int ii = (int)fl;
    const int ind = ((ii % 8) + 8) & 7;

    const float cost = cosf(theta), sint = sinf(theta);
    const float bin_h = rh / 7.0f, bin_w = rw / 7.0f;

    __shared__ int   s_off[4][NS];
    __shared__ float s_w[4][NS];

    if (tid < NS) {
        int iy = tid / 14, ix = tid - iy * 14;
        int py = iy >> 1, gy = iy & 1;
        int px = ix >> 1, gx = ix & 1;
        float yy = ((float)py + ((float)gy + 0.5f) * 0.5f) * bin_h - rh * 0.5f;
        float xx = ((float)px + ((float)gx + 0.5f) * 0.5f) * bin_w - rw * 0.5f;
        float x = xx * cost - yy * sint + cw;
        float y = xx * sint + yy * cost + ch;
        float vm = (y > -1.0f && y < 256.0f && x > -1.0f && x < 256.0f) ? 1.0f : 0.0f;
        float yc = fmaxf(y, 0.0f), xc = fmaxf(x, 0.0f);
        int y0 = (int)yc, x0 = (int)xc;
        int y1, x1; float yv, xv;
        if (y0 >= 255) { y0 = 255; y1 = 255; yv = 255.0f; }
        else           { y1 = y0 + 1; yv = yc; }
        if (x0 >= 255) { x0 = 255; x1 = 255; xv = 255.0f; }
        else           { x1 = x0 + 1; xv = xc; }
        float ly = yv - (float)y0, lx = xv - (float)x0;
        float hy = 1.0f - ly, hx = 1.0f - lx;
        s_w[0][tid] = hy * hx * vm;
        s_w[1][tid] = hy * lx * vm;
        s_w[2][tid] = ly * hx * vm;
        s_w[3][tid] = ly * lx * vm;
        int y0w = y0 << 8, y1w = y1 << 8;
        s_off[0][tid] = y0w + x0;
        s_off[1][tid] = y0w + x1;
        s_off[2][tid] = y1w + x0;
        s_off[3][tid] = y1w + x1;
    }
    __syncthreads();

    const float* fb = feat + (size_t)b * (256 * HW);

    const int ibeg = chunk * 784, iend = ibeg + 784;
    for (int i = ibeg + tid; i < iend; i += 256) {
        int c   = i / 49;
        int bin = i - c * 49;
        int py  = bin / 7;
        int px  = bin - py * 7;
        int sbase = py * 28 + px * 2;
        const int ss[4] = { sbase, sbase + 1, sbase + 14, sbase + 15 };

        int   off[4][4];
        float w[4][4];
        #pragma unroll
        for (int k = 0; k < 4; ++k) {
            #pragma unroll
            for (int cn = 0; cn < 4; ++cn) {
                off[k][cn] = s_off[cn][ss[k]];
                w[k][cn]   = s_w[cn][ss[k]];
            }
        }

        const float* fc = fb + (size_t)c * (8 * HW);
        float v[8];
        #pragma unroll
        for (int p = 0; p < 8; ++p) {
            const float* fp = fc + p * HW;
            float acc = 0.0f;
            #pragma unroll
            for (int k = 0; k < 4; ++k) {
                acc += w[k][0] * fp[off[k][0]]
                     + w[k][1] * fp[off[k][1]]
                     + w[k][2] * fp[off[k][2]]
                     + w[k][3] * fp[off[k][3]];
            }
            v[p] = acc;
        }

        float* ob = out + ((size_t)r * 256 + (size_t)c * 8) * 49 + bin;
        #pragma unroll
        for (int j = 0; j < 8; ++j) {
            int o = (ind + j) & 7;
            float res = 0.25f * (rvar * v[j] + lvar * v[(j + 1) & 7]);
            ob[(size_t)o * 49] = res;
        }
    }
}

extern "C" void kernel_launch(void* const* d_in, const int* in_sizes, int n_in,
                              void* d_out, int out_size, void* d_ws, size_t ws_size,
                              hipStream_t stream) {
    const float* feat = (const float*)d_in[0];   // 2*256*256*256 f32
    const float* rois = (const float*)d_in[1];   // 512*6 f32
    float* out = (float*)d_out;                  // 512*256*7*7 f32

    const size_t need = (size_t)2 * 256 * HW * sizeof(float);  // 134 MB
    if (ws_size >= need) {
        float* ft = (float*)d_ws;
        transpose_kernel<<<dim3(1024, 4, 2), dim3(256), 0, stream>>>(feat, ft);
        riroi_gather<<<dim3(512), dim3(256), 0, stream>>>(ft, rois, out);
    } else {
        riroi_kernel<<<dim3(512 * 2), dim3(256), 0, stream>>>(feat, rois, out);
    }
}

// Round 3
// 274.326 us; speedup vs baseline: 2.7898x; 1.2029x over previous
//
#include <hip/hip_runtime.h>

// RiRoIAlign on gfx950 — round 3.
// transpose NCHW->NHWC into ws, then gather with wave64-wide 1KB loads.
// R3 changes: gather uses 1024-thread blocks (32 waves/CU at 2 blocks/CU)
// and stages the per-roi output tile in LDS, writing back fully coalesced
// (fixes 3.4x write amplification from scattered 4B stores).

#define NS 196          // 14*14 sample points per roi
#define HW 65536        // 256*256
#define TWO_PI_F 6.283185307179586f
#define OPITCH 260      // LDS out-tile pitch (ch dim 256 + pad, mult of 4)

// ---------------- transpose: feat[b][ch][p] -> ft[b][p][ch] ----------------
__global__ __launch_bounds__(256) void transpose_kernel(
    const float* __restrict__ in, float* __restrict__ out)
{
    __shared__ float lds[64][65];
    const int tc = blockIdx.x;   // pixel tile (64 wide)
    const int tr = blockIdx.y;   // channel tile (64)
    const int b  = blockIdx.z;
    const int tid = threadIdx.x;

    const float* ip = in  + (size_t)b * 256 * HW;
    float*       op = out + (size_t)b * HW * 256;

    {
        int rr  = tid >> 4;          // 0..15
        int cc4 = (tid & 15) << 2;   // 0,4,..,60
        #pragma unroll
        for (int k = 0; k < 4; ++k) {
            int r = rr + (k << 4);
            const float4 v = *(const float4*)(ip + (size_t)(tr * 64 + r) * HW + tc * 64 + cc4);
            lds[r][cc4]     = v.x;
            lds[r][cc4 + 1] = v.y;
            lds[r][cc4 + 2] = v.z;
            lds[r][cc4 + 3] = v.w;
        }
    }
    __syncthreads();
    {
        int r4   = (tid & 15) << 2;  // 0,4,..,60 (channel within tile)
        int cseg = tid >> 4;         // 0..15
        #pragma unroll
        for (int k = 0; k < 4; ++k) {
            int c = cseg + (k << 4);
            float4 v;
            v.x = lds[r4][c]; v.y = lds[r4 + 1][c];
            v.z = lds[r4 + 2][c]; v.w = lds[r4 + 3][c];
            *(float4*)(op + (size_t)(tc * 64 + c) * 256 + tr * 64 + r4) = v;
        }
    }
}

// ---------------- gather from NHWC ----------------
__global__ __launch_bounds__(1024, 8) void riroi_gather(
    const float* __restrict__ ft, const float* __restrict__ rois,
    float* __restrict__ out)
{
    const int r = blockIdx.x;
    const int tid = threadIdx.x;
    const int lane = tid & 63;
    const int wave = tid >> 6;   // 0..15

    const float* roi = rois + r * 6;
    const int   b  = (int)roi[0];
    const float cw = roi[1] * 0.125f;
    const float ch = roi[2] * 0.125f;
    const float rw = fmaxf(roi[3] * 0.125f, 1.0f);
    const float rh = fmaxf(roi[4] * 0.125f, 1.0f);
    const float theta = roi[5];

    const float ind_f = theta * 8.0f / TWO_PI_F;
    const float fl    = floorf(ind_f);
    const float lvar  = ind_f - fl;
    const float rvar  = 1.0f - lvar;
    int ii = (int)fl;
    const int ind = ((ii % 8) + 8) & 7;

    const float cost = cosf(theta), sint = sinf(theta);
    const float bin_h = rh / 7.0f, bin_w = rw / 7.0f;

    __shared__ int   s_off[4][NS];
    __shared__ float s_w[4][NS];
    __shared__ float s_out[49 * OPITCH];   // [bin][ch], plane-space channels

    if (tid < NS) {
        int iy = tid / 14, ix = tid - iy * 14;
        int py = iy >> 1, gy = iy & 1;
        int px = ix >> 1, gx = ix & 1;
        float yy = ((float)py + ((float)gy + 0.5f) * 0.5f) * bin_h - rh * 0.5f;
        float xx = ((float)px + ((float)gx + 0.5f) * 0.5f) * bin_w - rw * 0.5f;
        float x = xx * cost - yy * sint + cw;
        float y = xx * sint + yy * cost + ch;
        float vm = (y > -1.0f && y < 256.0f && x > -1.0f && x < 256.0f) ? 1.0f : 0.0f;
        float yc = fmaxf(y, 0.0f), xc = fmaxf(x, 0.0f);
        int y0 = (int)yc, x0 = (int)xc;
        int y1, x1; float yv, xv;
        if (y0 >= 255) { y0 = 255; y1 = 255; yv = 255.0f; }
        else           { y1 = y0 + 1; yv = yc; }
        if (x0 >= 255) { x0 = 255; x1 = 255; xv = 255.0f; }
        else           { x1 = x0 + 1; xv = xc; }
        float ly = yv - (float)y0, lx = xv - (float)x0;
        float hy = 1.0f - ly, hx = 1.0f - lx;
        s_w[0][tid] = hy * hx * vm;
        s_w[1][tid] = hy * lx * vm;
        s_w[2][tid] = ly * hx * vm;
        s_w[3][tid] = ly * lx * vm;
        int y0w = y0 << 8, y1w = y1 << 8;
        s_off[0][tid] = y0w + x0;
        s_off[1][tid] = y0w + x1;
        s_off[2][tid] = y1w + x0;
        s_off[3][tid] = y1w + x1;
    }
    __syncthreads();

    const float* fb = ft + (size_t)b * ((size_t)HW * 256) + (lane << 2);

    for (int bin = wave; bin < 49; bin += 16) {
        int py = bin / 7, px = bin - py * 7;
        int sbase = py * 28 + px * 2;
        float4 acc = make_float4(0.f, 0.f, 0.f, 0.f);
        #pragma unroll
        for (int k = 0; k < 4; ++k) {
            int s = sbase + ((k & 1) ? 1 : 0) + ((k & 2) ? 14 : 0);
            #pragma unroll
            for (int cn = 0; cn < 4; ++cn) {
                int   o = s_off[cn][s];
                float w = s_w[cn][s];
                const float4 f = *(const float4*)(fb + (size_t)o * 256);
                acc.x += w * f.x; acc.y += w * f.y;
                acc.z += w * f.z; acc.w += w * f.w;
            }
        }
        // orientation blend in plane space: element i holds plane j=(4*lane+i)&7
        float nx = __shfl_xor(acc.x, 1);
        float4 res;
        res.x = 0.25f * (rvar * acc.x + lvar * acc.y);
        res.y = 0.25f * (rvar * acc.y + lvar * acc.z);
        res.z = 0.25f * (rvar * acc.z + lvar * acc.w);
        res.w = 0.25f * (rvar * acc.w + lvar * nx);
        // stage unpermuted (plane-space channel = 4*lane+i); conflict-free b128
        *(float4*)&s_out[bin * OPITCH + (lane << 2)] = res;
    }
    __syncthreads();

    // coalesced writeback with orientation permutation:
    // out ch_out -> plane-space ch_in = (ch_out & ~7) | ((ch_out + (8-ind)) & 7)
    const int ind_neg = (8 - ind) & 7;
    float* ob = out + (size_t)r * 12544;
    for (int i = tid << 2; i < 12544; i += 4096) {
        float4 v;
        #pragma unroll
        for (int q = 0; q < 4; ++q) {
            int j   = i + q;
            int co  = j / 49;
            int bin = j - co * 49;
            int ci  = (co & ~7) | ((co + ind_neg) & 7);
            ((float*)&v)[q] = s_out[bin * OPITCH + ci];
        }
        *(float4*)(ob + i) = v;
    }
}

extern "C" void kernel_launch(void* const* d_in, const int* in_sizes, int n_in,
                              void* d_out, int out_size, void* d_ws, size_t ws_size,
                              hipStream_t stream) {
    const float* feat = (const float*)d_in[0];   // 2*256*256*256 f32
    const float* rois = (const float*)d_in[1];   // 512*6 f32
    float* out = (float*)d_out;                  // 512*256*7*7 f32

    float* ft = (float*)d_ws;
    transpose_kernel<<<dim3(1024, 4, 2), dim3(256), 0, stream>>>(feat, ft);
    riroi_gather<<<dim3(512), dim3(1024), 0, stream>>>(ft, rois, out);
}

// Round 4
// 250.998 us; speedup vs baseline: 3.0490x; 1.0929x over previous
//
#include <hip/hip_runtime.h>

// RiRoIAlign on gfx950 — round 4.
// Stage features as fp16 NHWC in ws (halves transpose-write and gather-fetch
// bytes; convex-combination downstream => error << threshold).
// Transpose: 32ch x 256px tiles, 1KB-contiguous channel-row reads, register
// 4x4 transpose, b128 LDS ops, 64B-aligned fp16 row-segment writes.
// Gather: lane holds 8 channels (= all 8 orientation planes) -> in-lane blend;
// wave loads 2 corners per instruction (2 x 512B segments); output tile staged
// in LDS and written back fully coalesced with the orientation permutation.

#include <hip/hip_fp16.h>

typedef _Float16 h16;
typedef _Float16 h8 __attribute__((ext_vector_type(8)));   // 16 B

#define NS 196          // 14*14 sample points per roi
#define HW 65536        // 256*256
#define TWO_PI_F 6.283185307179586f
#define OPITCH 260      // gather LDS out-tile pitch
#define TP 40           // transpose LDS pitch in halves (80 B, 16B-aligned rows)

// ------- transpose+cvt: feat[b][ch][px] f32 -> ft[b][px][ch] f16 -------
__global__ __launch_bounds__(256) void transpose_kernel(
    const float* __restrict__ in, h16* __restrict__ out)
{
    __shared__ h16 lds[256 * TP];     // [px 0..255][ch 0..31], pitch TP
    const int t = threadIdx.x;
    const int a = t & 63;             // pixel/4 index within tile
    const int w = t >> 6;             // wave: channel octet

    const int b  = blockIdx.z;
    const int tc = blockIdx.y;        // channel tile (32 ch)
    const int tp = blockIdx.x;        // pixel tile (256 px)

    const float* ip = in + ((size_t)b * 256 + tc * 32 + w * 8) * HW + tp * 256 + a * 4;

    float4 v[8];
    #pragma unroll
    for (int j = 0; j < 8; ++j)
        v[j] = *(const float4*)(ip + (size_t)j * HW);   // ch w*8+j, px 4a..4a+3

    #pragma unroll
    for (int p = 0; p < 4; ++p) {
        h8 row;
        #pragma unroll
        for (int j = 0; j < 8; ++j)
            row[j] = (h16)(((const float*)&v[j])[p]);
        *(h8*)&lds[(a * 4 + p) * TP + w * 8] = row;
    }
    __syncthreads();

    h16* op = out + ((size_t)b * HW + (size_t)tp * 256) * 256 + tc * 32;
    #pragma unroll
    for (int k = 0; k < 4; ++k) {
        int px   = (t >> 2) + k * 64;
        int part = t & 3;
        h8 r = *(const h8*)&lds[px * TP + part * 8];
        *(h8*)(op + (size_t)px * 256 + part * 8) = r;   // 64B-aligned segments
    }
}

// ---------------- gather from fp16 NHWC ----------------
__global__ __launch_bounds__(1024, 8) void riroi_gather(
    const h16* __restrict__ ft, const float* __restrict__ rois,
    float* __restrict__ out)
{
    const int r = blockIdx.x;
    const int tid  = threadIdx.x;
    const int lane = tid & 63;
    const int wave = tid >> 6;       // 0..15
    const int l32  = lane & 31;
    const int hi   = lane >> 5;      // corner-pair selector

    const float* roi = rois + r * 6;
    const int   b  = (int)roi[0];
    const float cw = roi[1] * 0.125f;
    const float ch = roi[2] * 0.125f;
    const float rw = fmaxf(roi[3] * 0.125f, 1.0f);
    const float rh = fmaxf(roi[4] * 0.125f, 1.0f);
    const float theta = roi[5];

    const float ind_f = theta * 8.0f / TWO_PI_F;
    const float fl    = floorf(ind_f);
    const float lvar  = ind_f - fl;
    const float rvar  = 1.0f - lvar;
    int ii = (int)fl;
    const int ind = ((ii % 8) + 8) & 7;

    const float cost = cosf(theta), sint = sinf(theta);
    const float bin_h = rh / 7.0f, bin_w = rw / 7.0f;

    __shared__ int   s_off[4][NS];
    __shared__ float s_w[4][NS];
    __shared__ float s_out[49 * OPITCH];   // [bin][ch] plane-space

    if (tid < NS) {
        int iy = tid / 14, ix = tid - iy * 14;
        int py = iy >> 1, gy = iy & 1;
        int px = ix >> 1, gx = ix & 1;
        float yy = ((float)py + ((float)gy + 0.5f) * 0.5f) * bin_h - rh * 0.5f;
        float xx = ((float)px + ((float)gx + 0.5f) * 0.5f) * bin_w - rw * 0.5f;
        float x = xx * cost - yy * sint + cw;
        float y = xx * sint + yy * cost + ch;
        float vm = (y > -1.0f && y < 256.0f && x > -1.0f && x < 256.0f) ? 1.0f : 0.0f;
        float yc = fmaxf(y, 0.0f), xc = fmaxf(x, 0.0f);
        int y0 = (int)yc, x0 = (int)xc;
        int y1, x1; float yv, xv;
        if (y0 >= 255) { y0 = 255; y1 = 255; yv = 255.0f; }
        else           { y1 = y0 + 1; yv = yc; }
        if (x0 >= 255) { x0 = 255; x1 = 255; xv = 255.0f; }
        else           { x1 = x0 + 1; xv = xc; }
        float ly = yv - (float)y0, lx = xv - (float)x0;
        float hy = 1.0f - ly, hx = 1.0f - lx;
        s_w[0][tid] = hy * hx * vm;
        s_w[1][tid] = hy * lx * vm;
        s_w[2][tid] = ly * hx * vm;
        s_w[3][tid] = ly * lx * vm;
        int y0w = y0 << 8, y1w = y1 << 8;
        s_off[0][tid] = y0w + x0;
        s_off[1][tid] = y0w + x1;
        s_off[2][tid] = y1w + x0;
        s_off[3][tid] = y1w + x1;
    }
    __syncthreads();

    const h16* fb = ft + (size_t)b * ((size_t)HW * 256) + (l32 << 3);

    for (int bin = wave; bin < 49; bin += 16) {
        int py = bin / 7, px = bin - py * 7;
        int sbase = py * 28 + px * 2;
        float v[8] = {0.f, 0.f, 0.f, 0.f, 0.f, 0.f, 0.f, 0.f};
        #pragma unroll
        for (int k = 0; k < 4; ++k) {
            int s = sbase + ((k & 1) ? 1 : 0) + ((k & 2) ? 14 : 0);
            #pragma unroll
            for (int cnp = 0; cnp < 2; ++cnp) {
                int   cn  = cnp * 2 + hi;
                int   o   = s_off[cn][s];
                float wgt = s_w[cn][s];
                h8 f = *(const h8*)(fb + (size_t)o * 256);
                #pragma unroll
                for (int i = 0; i < 8; ++i)
                    v[i] += wgt * (float)f[i];
            }
        }
        // fold the two corner-half lanes together
        #pragma unroll
        for (int i = 0; i < 8; ++i)
            v[i] += __shfl_xor(v[i], 32);

        if (hi == 0) {
            // in-lane orientation blend: element i IS plane j=i (ch = 32*l32.. +i)
            float res[8];
            #pragma unroll
            for (int i = 0; i < 8; ++i)
                res[i] = 0.25f * (rvar * v[i] + lvar * v[(i + 1) & 7]);
            float* dst = &s_out[bin * OPITCH + (l32 << 3)];
            *(float4*)dst       = make_float4(res[0], res[1], res[2], res[3]);
            *(float4*)(dst + 4) = make_float4(res[4], res[5], res[6], res[7]);
        }
    }
    __syncthreads();

    // coalesced writeback with orientation permutation:
    // ch_out -> plane-space ch_in = (ch_out & ~7) | ((ch_out + (8-ind)) & 7)
    const int ind_neg = (8 - ind) & 7;
    float* ob = out + (size_t)r * 12544;
    for (int i = tid << 2; i < 12544; i += 4096) {
        float4 vo;
        #pragma unroll
        for (int q = 0; q < 4; ++q) {
            int j   = i + q;
            int co  = j / 49;
            int bin = j - co * 49;
            int ci  = (co & ~7) | ((co + ind_neg) & 7);
            ((float*)&vo)[q] = s_out[bin * OPITCH + ci];
        }
        *(float4*)(ob + i) = vo;
    }
}

extern "C" void kernel_launch(void* const* d_in, const int* in_sizes, int n_in,
                              void* d_out, int out_size, void* d_ws, size_t ws_size,
                              hipStream_t stream) {
    const float* feat = (const float*)d_in[0];   // 2*256*256*256 f32
    const float* rois = (const float*)d_in[1];   // 512*6 f32
    float* out = (float*)d_out;                  // 512*256*7*7 f32

    h16* ft = (h16*)d_ws;                        // 2*65536*256 f16 = 67 MB
    transpose_kernel<<<dim3(256, 8, 2), dim3(256), 0, stream>>>(feat, ft);
    riroi_gather<<<dim3(512), dim3(1024), 0, stream>>>(ft, rois, out);
}

// Round 5
// 248.915 us; speedup vs baseline: 3.0746x; 1.0084x over previous
//
#include <hip/hip_runtime.h>
#include <hip/hip_fp16.h>

// RiRoIAlign on gfx950 — round 5.
// fp16 NHWC staging in ws + channel-split gather.
// Gather: 1024 blocks (roi, ch-half of 128), 512 threads (8 waves, 4 blocks/CU
// = 32 waves/CU). Per bin the full wave covers all 4 bilinear corners at once
// (lane = corner*16 + chgroup; one h8 load per sample point), folded with two
// shfl_xor. 49 bins / 8 waves -> critical path 7 vs 6.1 mean (was 4 vs 3.06).
// Out tile staged in LDS (26 KB), written back fully coalesced with the
// orientation permutation (permutation is octet-local, so ch-split is safe).

typedef _Float16 h16;
typedef _Float16 h8 __attribute__((ext_vector_type(8)));   // 16 B

#define NS 196          // 14*14 sample points per roi
#define HW 65536        // 256*256
#define TWO_PI_F 6.283185307179586f
#define OPITCH 132      // gather LDS out-tile pitch (128 ch + pad)
#define TP 40           // transpose LDS pitch in halves

// ------- transpose+cvt: feat[b][ch][px] f32 -> ft[b][px][ch] f16 -------
__global__ __launch_bounds__(256) void transpose_kernel(
    const float* __restrict__ in, h16* __restrict__ out)
{
    __shared__ h16 lds[256 * TP];     // [px 0..255][ch 0..31], pitch TP
    const int t = threadIdx.x;
    const int a = t & 63;             // pixel/4 index within tile
    const int w = t >> 6;             // wave: channel octet

    const int b  = blockIdx.z;
    const int tc = blockIdx.y;        // channel tile (32 ch)
    const int tp = blockIdx.x;        // pixel tile (256 px)

    const float* ip = in + ((size_t)b * 256 + tc * 32 + w * 8) * HW + tp * 256 + a * 4;

    float4 v[8];
    #pragma unroll
    for (int j = 0; j < 8; ++j)
        v[j] = *(const float4*)(ip + (size_t)j * HW);   // ch w*8+j, px 4a..4a+3

    #pragma unroll
    for (int p = 0; p < 4; ++p) {
        h8 row;
        #pragma unroll
        for (int j = 0; j < 8; ++j)
            row[j] = (h16)(((const float*)&v[j])[p]);
        *(h8*)&lds[(a * 4 + p) * TP + w * 8] = row;
    }
    __syncthreads();

    h16* op = out + ((size_t)b * HW + (size_t)tp * 256) * 256 + tc * 32;
    #pragma unroll
    for (int k = 0; k < 4; ++k) {
        int px   = (t >> 2) + k * 64;
        int part = t & 3;
        h8 r = *(const h8*)&lds[px * TP + part * 8];
        *(h8*)(op + (size_t)px * 256 + part * 8) = r;   // 1KB contiguous per wave
    }
}

// ---------------- gather from fp16 NHWC, channel-split ----------------
__global__ __launch_bounds__(512, 8) void riroi_gather(
    const h16* __restrict__ ft, const float* __restrict__ rois,
    float* __restrict__ out)
{
    const int r    = blockIdx.x >> 1;
    const int half = blockIdx.x & 1;     // ch 0..127 or 128..255
    const int tid  = threadIdx.x;
    const int lane = tid & 63;
    const int wave = tid >> 6;           // 0..7
    const int cn   = lane >> 4;          // bilinear corner 0..3
    const int chg  = lane & 15;          // channel group (8 ch each)

    const float* roi = rois + r * 6;
    const int   b  = (int)roi[0];
    const float cw = roi[1] * 0.125f;
    const float ch = roi[2] * 0.125f;
    const float rw = fmaxf(roi[3] * 0.125f, 1.0f);
    const float rh = fmaxf(roi[4] * 0.125f, 1.0f);
    const float theta = roi[5];

    const float ind_f = theta * 8.0f / TWO_PI_F;
    const float fl    = floorf(ind_f);
    const float lvar  = ind_f - fl;
    const float rvar  = 1.0f - lvar;
    int ii = (int)fl;
    const int ind = ((ii % 8) + 8) & 7;

    const float cost = cosf(theta), sint = sinf(theta);
    const float bin_h = rh / 7.0f, bin_w = rw / 7.0f;

    __shared__ int   s_off[4][NS];       // row offset * 256 (element offset)
    __shared__ float s_w[4][NS];
    __shared__ float s_out[49 * OPITCH]; // [bin][ch-half] plane-space

    if (tid < NS) {
        int iy = tid / 14, ix = tid - iy * 14;
        int py = iy >> 1, gy = iy & 1;
        int px = ix >> 1, gx = ix & 1;
        float yy = ((float)py + ((float)gy + 0.5f) * 0.5f) * bin_h - rh * 0.5f;
        float xx = ((float)px + ((float)gx + 0.5f) * 0.5f) * bin_w - rw * 0.5f;
        float x = xx * cost - yy * sint + cw;
        float y = xx * sint + yy * cost + ch;
        float vm = (y > -1.0f && y < 256.0f && x > -1.0f && x < 256.0f) ? 1.0f : 0.0f;
        float yc = fmaxf(y, 0.0f), xc = fmaxf(x, 0.0f);
        int y0 = (int)yc, x0 = (int)xc;
        int y1, x1; float yv, xv;
        if (y0 >= 255) { y0 = 255; y1 = 255; yv = 255.0f; }
        else           { y1 = y0 + 1; yv = yc; }
        if (x0 >= 255) { x0 = 255; x1 = 255; xv = 255.0f; }
        else           { x1 = x0 + 1; xv = xc; }
        float ly = yv - (float)y0, lx = xv - (float)x0;
        float hy = 1.0f - ly, hx = 1.0f - lx;
        s_w[0][tid] = hy * hx * vm;
        s_w[1][tid] = hy * lx * vm;
        s_w[2][tid] = ly * hx * vm;
        s_w[3][tid] = ly * lx * vm;
        int y0w = y0 << 8, y1w = y1 << 8;
        s_off[0][tid] = (y0w + x0) << 8;   // pre-scaled by 256 channels
        s_off[1][tid] = (y0w + x1) << 8;
        s_off[2][tid] = (y1w + x0) << 8;
        s_off[3][tid] = (y1w + x1) << 8;
    }
    __syncthreads();

    const h16* fb = ft + (size_t)b * ((size_t)HW * 256) + half * 128 + (chg << 3);

    for (int bin = wave; bin < 49; bin += 8) {
        int py = bin / 7, px = bin - py * 7;
        int sbase = py * 28 + px * 2;
        float v[8] = {0.f, 0.f, 0.f, 0.f, 0.f, 0.f, 0.f, 0.f};
        #pragma unroll
        for (int k = 0; k < 4; ++k) {
            int   s   = sbase + (k & 1) + ((k & 2) ? 14 : 0);
            int   o   = s_off[cn][s];
            float wgt = s_w[cn][s];
            h8 f = *(const h8*)(fb + o);
            #pragma unroll
            for (int i = 0; i < 8; ++i)
                v[i] += wgt * (float)f[i];
        }
        // fold the 4 corner groups (lanes cn*16+chg)
        #pragma unroll
        for (int i = 0; i < 8; ++i) {
            v[i] += __shfl_xor(v[i], 16);
            v[i] += __shfl_xor(v[i], 32);
        }
        if (cn == 0) {
            // in-lane orientation blend: element i IS plane j=i
            float res[8];
            #pragma unroll
            for (int i = 0; i < 8; ++i)
                res[i] = 0.25f * (rvar * v[i] + lvar * v[(i + 1) & 7]);
            float* dst = &s_out[bin * OPITCH + (chg << 3)];
            *(float4*)dst       = make_float4(res[0], res[1], res[2], res[3]);
            *(float4*)(dst + 4) = make_float4(res[4], res[5], res[6], res[7]);
        }
    }
    __syncthreads();

    // coalesced writeback with orientation permutation (octet-local)
    const int ind_neg = (8 - ind) & 7;
    float* ob = out + (size_t)r * 12544 + half * 6272;
    for (int i = tid << 2; i < 6272; i += 2048) {
        float4 vo;
        #pragma unroll
        for (int q = 0; q < 4; ++q) {
            int j   = i + q;
            int co  = j / 49;            // local channel 0..127
            int bin = j - co * 49;
            int ci  = (co & ~7) | ((co + ind_neg) & 7);
            ((float*)&vo)[q] = s_out[bin * OPITCH + ci];
        }
        *(float4*)(ob + i) = vo;
    }
}

extern "C" void kernel_launch(void* const* d_in, const int* in_sizes, int n_in,
                              void* d_out, int out_size, void* d_ws, size_t ws_size,
                              hipStream_t stream) {
    const float* feat = (const float*)d_in[0];   // 2*256*256*256 f32
    const float* rois = (const float*)d_in[1];   // 512*6 f32
    float* out = (float*)d_out;                  // 512*256*7*7 f32

    h16* ft = (h16*)d_ws;                        // 2*65536*256 f16 = 67 MB
    transpose_kernel<<<dim3(256, 8, 2), dim3(256), 0, stream>>>(feat, ft);
    riroi_gather<<<dim3(1024), dim3(512), 0, stream>>>(ft, rois, out);
}